// Round 3
// baseline (152.155 us; speedup 1.0000x reference)
//
#include <hip/hip_runtime.h>
#include <hip/hip_fp16.h>
#include <math.h>

#define L 252
#define HID 768
#define MLP 770
#define NLAB 36
#define NB 2
#define M1 (NB*L)         // 504
#define N1 (2*MLP)        // 1540
#define LL (L*L)          // 63504
#define LL4 (LL/4)        // 15876
#define KC 25             // main K chunks (800 = 25*32)
#define KC1 24            // gemm1 K chunks (768 = 24*32)
#define NT1P 100          // W1F n-tiles (legacy layout constant)
#define NMT 32            // VBF m-tiles (legacy layout constant)

typedef float f32x4 __attribute__((ext_vector_type(4)));
typedef _Float16 half8 __attribute__((ext_vector_type(8)));
typedef _Float16 half2v __attribute__((ext_vector_type(2)));

// ---- ws layout (floats) ----
#define AJF_OFF 0                               // fp16 [2][25][16 jt][64][8]
#define AJF_FLOATS 204800
#define AIB_OFF (AJF_OFF + AJF_FLOATS)          // fp16 [3][504][800]
#define AIB_FLOATS 604800
#define W2F_OFF (AIB_OFF + AIB_FLOATS)          // uint4 [25][3][64]
#define W2F_FLOATS 19200
#define PART_OFF (W2F_OFF + W2F_FLOATS)         // float2 [72][1024]
#define PART_FLOATS (72*1024*2)
#define NW2F (KC*3*64)

__device__ __forceinline__ void dma16(const void* g, void* l) {
  __builtin_amdgcn_global_load_lds(
      (const __attribute__((address_space(1))) unsigned int*)g,
      (__attribute__((address_space(3))) unsigned int*)l, 16, 0, 0);
}

__device__ __forceinline__ unsigned short f16b(float x) {
  _Float16 h = (_Float16)x;
  return *reinterpret_cast<unsigned short*>(&h);
}

// gfx9 s_waitcnt imm: vmcnt[3:0] | expcnt<<4 | lgkmcnt<<8 | vmcnt_hi<<14
#define WAIT_VM5() __builtin_amdgcn_s_waitcnt(0x0F75)   // vmcnt(5)

// ---------------------------------------------------------------------------
// GEMM1 (self-packing; replaces pack_kernel + old gemm1):
//  - phase 0: block packs its own W1F slice [24 kc][2 nt][64] fp16 frags into
//    LDS (48 KB) via scalar dword loads (W1 row stride 1537 fp32 is 16B-
//    misaligned; dwords are always safe). by==0 blocks also pack W2F -> ws
//    for main_kernel (visibility via kernel boundary).
//  - K-loop: A-fragments loaded DIRECTLY from hidden (fp32, 16B-aligned) into
//    regs with 1-ahead prefetch, cvt to fp16 (RTE, matches old pack), MFMA
//    against LDS-resident B. No global_load_lds, no vmcnt gymnastics.
// Grid (50, 8), 4 waves; 3 blocks/CU (48 KB LDS).
// ---------------------------------------------------------------------------
__global__ __launch_bounds__(256, 3) void gemm1_kernel(
    const float* __restrict__ b1, const float* __restrict__ W1,
    const float* __restrict__ W2, const float* __restrict__ hidden,
    float* __restrict__ ws, unsigned short* __restrict__ AJF,
    unsigned short* __restrict__ AiBh) {
  __shared__ char sm[49152];
  int t = threadIdx.x;
  int wave = t >> 6, lane = t & 63, lj = lane & 15, kh = lane >> 4;
  int nt0 = blockIdx.x * 2;
  int mt = blockIdx.y * 4 + wave;
  int m0 = mt * 16;
  union FU { unsigned u[4]; half8 h8; };

  // --- side job: W2F pack (50 by==0 blocks x 96 entries = 4800) ---
  if (blockIdx.y == 0 && t < 96) {
    int e2 = blockIdx.x * 96 + t;
    int kc = e2 / 192, rem = e2 - kc * 192;
    int tile = rem / 64, ln = rem - tile * 64;
    int label = tile * 16 + (ln & 15);
    int kb = kc * 32 + (ln >> 4) * 8;
    unsigned int u[4];
#pragma unroll
    for (int p = 0; p < 4; p++) {
      unsigned short us[2];
#pragma unroll
      for (int q = 0; q < 2; q++) {
        int k = kb + 2 * p + q;
        float v = (label < NLAB && k < MLP) ? W2[label * MLP + k] : 0.f;
        us[q] = f16b(v);
      }
      u[p] = (unsigned int)us[0] | ((unsigned int)us[1] << 16);
    }
    ((uint4*)(ws + W2F_OFF))[e2] = make_uint4(u[0], u[1], u[2], u[3]);
  }

  // --- phase 0: pack this block's W1F slice into LDS (3072 entries) ---
#pragma unroll
  for (int r = 0; r < 12; r++) {
    int e = t + 256 * r;
    int le = e & 63, ntt = (e >> 6) & 1, kcc = e >> 7;
    int n = (nt0 + ntt) * 16 + (le & 15);
    int kb = kcc * 32 + (le >> 4) * 8;
    unsigned int u[4];
#pragma unroll
    for (int p = 0; p < 4; p++) {
      unsigned short us[2];
#pragma unroll
      for (int q = 0; q < 2; q++) {
        int k = kb + 2 * p + q;
        float v = 0.f;
        if (n < N1) v = (n < MLP) ? W1[(size_t)n * 1537 + k]
                                  : W1[(size_t)(n - MLP) * 1537 + HID + k];
        us[q] = f16b(v);
      }
      u[p] = (unsigned int)us[0] | ((unsigned int)us[1] << 16);
    }
    *(uint4*)(sm + (size_t)e * 16) = make_uint4(u[0], u[1], u[2], u[3]);
  }
  __syncthreads();

  // --- K-loop: direct-A (reg prefetch) x LDS-resident B ---
  int mrow = m0 + lj;
  const bool mvalid = mrow < M1;
  if (mrow >= M1) mrow = M1 - 1;
  int bb = (mrow >= L) ? 1 : 0;
  const float* aptr = hidden + ((size_t)(bb * (L + 1) + 1 + (mrow - bb * L))) * HID + kh * 8;

  f32x4 acc[2];
  acc[0] = (f32x4)(0.f);
  acc[1] = (f32x4)(0.f);
  float4 pa0 = *(const float4*)(aptr);
  float4 pa1 = *(const float4*)(aptr + 4);

  for (int kc = 0; kc < KC1; kc++) {
    float4 c0 = pa0, c1 = pa1;
    int kn = (kc < KC1 - 1) ? kc + 1 : kc;
    pa0 = *(const float4*)(aptr + kn * 32);
    pa1 = *(const float4*)(aptr + kn * 32 + 4);
    uint4 bv0 = *(const uint4*)(sm + (size_t)(kc * 2 + 0) * 1024 + lane * 16);
    uint4 bv1 = *(const uint4*)(sm + (size_t)(kc * 2 + 1) * 1024 + lane * 16);
    float cf[8] = {c0.x, c0.y, c0.z, c0.w, c1.x, c1.y, c1.z, c1.w};
    FU af;
#pragma unroll
    for (int p = 0; p < 4; p++) {
      float f0 = mvalid ? cf[2 * p] : 0.f;
      float f1 = mvalid ? cf[2 * p + 1] : 0.f;
      af.u[p] = (unsigned int)f16b(f0) | ((unsigned int)f16b(f1) << 16);
    }
    FU bf0, bf1;
    bf0.u[0] = bv0.x; bf0.u[1] = bv0.y; bf0.u[2] = bv0.z; bf0.u[3] = bv0.w;
    bf1.u[0] = bv1.x; bf1.u[1] = bv1.y; bf1.u[2] = bv1.z; bf1.u[3] = bv1.w;
    acc[0] = __builtin_amdgcn_mfma_f32_16x16x32_f16(af.h8, bf0.h8, acc[0], 0, 0, 0);
    acc[1] = __builtin_amdgcn_mfma_f32_16x16x32_f16(af.h8, bf1.h8, acc[1], 0, 0, 0);
  }

  // --- epilogue: identical semantics to previous gemm1 ---
#pragma unroll
  for (int nt = 0; nt < 2; nt++) {
    int nn = (nt0 + nt) * 16 + lj;
    if (nn >= N1) continue;
    if (nn < MLP) {
      float b1v = b1[nn];
      float wv = W1[(size_t)nn * 1537 + 1536];
#pragma unroll
      for (int r = 0; r < 4; r++) {
        int mm = m0 + kh * 4 + r;
        if (mm < M1) {
          float a = acc[nt][r] + b1v;
          AiBh[(size_t)(0 * M1 + mm) * 800 + nn] = f16b(a);
          AiBh[(size_t)(1 * M1 + mm) * 800 + nn] = f16b(a + wv);
          AiBh[(size_t)(2 * M1 + mm) * 800 + nn] = f16b(a + 2.f * wv);
        }
      }
    } else {
      int hh = nn - MLP;
      int kcq = hh >> 5, kk = hh & 31;
      int l2hi = (kk >> 3) << 4, ee = kk & 7;
#pragma unroll
      for (int r = 0; r < 4; r++) {
        int mm = m0 + kh * 4 + r;
        if (mm < M1) {
          int bb2 = (mm >= L) ? 1 : 0;
          int jg = mm - bb2 * L;
          size_t rec = ((size_t)((bb2 * KC + kcq) * 16 + (jg >> 4)) * 64 + (l2hi | (jg & 15)));
          AJF[rec * 8 + ee] = f16b(acc[nt][r]);
        }
      }
    }
  }
}

// ---------------------------------------------------------------------------
// Main: per-wave async pipeline, 2-ahead / 3 buffers, vmcnt(5). fp16 packed
// h-construction: v_pk_add_f16 + v_pk_max_f16 -> mfma_f16 (no repack).
// Block = 64j x 4i x b; wave = j-16-tile. Buf 5KB: aj[0,1K) p[1K,2K) wf[2K,5K).
// ---------------------------------------------------------------------------
__global__ __launch_bounds__(256, 2) void main_kernel(
    const unsigned short* __restrict__ AJF,
    const unsigned short* __restrict__ AiBh,
    const uint4* __restrict__ wfr,
    const float* __restrict__ b2,
    const int* __restrict__ spans,
    const int* __restrict__ smask,
    float* __restrict__ out,
    float* __restrict__ part) {
  __shared__ char sm[61440];
  int t = threadIdx.x;
  int wave = t >> 6, lane = t & 63, lj = lane & 15, kh = lane >> 4;
  int j0 = blockIdx.x * 64;
  int i0 = blockIdx.y * 4;
  int b = blockIdx.z;
  int s = spans[2 * b], e = spans[2 * b + 1];
  int j = j0 + wave * 16 + lj;

  int poff[4];
#pragma unroll
  for (int ii = 0; ii < 4; ii++) {
    int i = i0 + ii;
    int ind = 0;
    if (i == s && j == e) ind = 2;
    else if (s <= i && i <= j && j <= e) ind = 1;
    poff[ii] = 1024 + ((ind * 4 + ii) * 4 + kh) * 16;
  }

  const unsigned short* aj_g = AJF + ((size_t)((b * KC + 0) * 16 + (j0 >> 4) + wave) * 64 + lane) * 8;
  int pr = lane >> 2; if (pr > 11) pr = 11;
  int pt = pr >> 2, pii = pr & 3, pc = lane & 3;
  const unsigned short* p_g = AiBh + (size_t)(pt * M1 + b * L + i0 + pii) * 800 + pc * 8;
  const uint4* wf_g = wfr + lane;
  char* WB = sm + wave * 15360;
  char* bA = WB;
  char* bB = WB + 5120;
  char* bC = WB + 10240;

  f32x4 acc[4][3];
#pragma unroll
  for (int ii = 0; ii < 4; ii++)
#pragma unroll
    for (int tl = 0; tl < 3; tl++) acc[ii][tl] = (f32x4)(0.f);
  union FU { unsigned u[4]; half8 h8; };
  union U2 { unsigned u; half2v h; };

  dma16(aj_g, bA);
  dma16(p_g, bA + 1024);
  dma16(&wf_g[0 * 64], bA + 2048);
  dma16(&wf_g[1 * 64], bA + 3072);
  dma16(&wf_g[2 * 64], bA + 4096);
  dma16(aj_g + 8192, bB);
  dma16(p_g + 32, bB + 1024);
  dma16(&wf_g[3 * 64], bB + 2048);
  dma16(&wf_g[4 * 64], bB + 3072);
  dma16(&wf_g[5 * 64], bB + 4096);

  for (int kc = 0; kc < KC; kc++) {
    WAIT_VM5();
    uint4 av = *(const uint4*)(bA + lane * 16);
    uint4 w0 = *(const uint4*)(bA + 2048 + lane * 16);
    uint4 w1 = *(const uint4*)(bA + 3072 + lane * 16);
    uint4 w2v = *(const uint4*)(bA + 4096 + lane * 16);
    uint4 pv[4];
#pragma unroll
    for (int ii = 0; ii < 4; ii++) pv[ii] = *(const uint4*)(bA + poff[ii]);
    __builtin_amdgcn_sched_barrier(0);
    int kn = kc + 2; if (kn > KC - 1) kn = KC - 1;
    dma16(aj_g + (size_t)kn * 8192, bC);
    dma16(p_g + kn * 32, bC + 1024);
    dma16(&wf_g[(kn * 3 + 0) * 64], bC + 2048);
    dma16(&wf_g[(kn * 3 + 1) * 64], bC + 3072);
    dma16(&wf_g[(kn * 3 + 2) * 64], bC + 4096);
    __builtin_amdgcn_sched_barrier(0);
    { char* tmp = bA; bA = bB; bB = bC; bC = tmp; }
    unsigned avu[4] = {av.x, av.y, av.z, av.w};
    FU wf0, wf1, wf2;
    wf0.u[0] = w0.x; wf0.u[1] = w0.y; wf0.u[2] = w0.z; wf0.u[3] = w0.w;
    wf1.u[0] = w1.x; wf1.u[1] = w1.y; wf1.u[2] = w1.z; wf1.u[3] = w1.w;
    wf2.u[0] = w2v.x; wf2.u[1] = w2v.y; wf2.u[2] = w2v.z; wf2.u[3] = w2v.w;
#pragma unroll
    for (int ii = 0; ii < 4; ii++) {
      unsigned pu[4] = {pv[ii].x, pv[ii].y, pv[ii].z, pv[ii].w};
      FU fr;
#pragma unroll
      for (int q = 0; q < 4; q++) {
        U2 a, p, r;
        a.u = avu[q]; p.u = pu[q];
        half2v sum = a.h + p.h;                       // v_pk_add_f16
        half2v zz = (half2v)((_Float16)0);
        r.h = __builtin_elementwise_max(sum, zz);     // v_pk_max_f16
        fr.u[q] = r.u;
      }
      acc[ii][0] = __builtin_amdgcn_mfma_f32_16x16x32_f16(fr.h8, wf0.h8, acc[ii][0], 0, 0, 0);
      acc[ii][1] = __builtin_amdgcn_mfma_f32_16x16x32_f16(fr.h8, wf1.h8, acc[ii][1], 0, 0, 0);
      acc[ii][2] = __builtin_amdgcn_mfma_f32_16x16x32_f16(fr.h8, wf2.h8, acc[ii][2], 0, 0, 0);
    }
  }

  // Epilogue: masked store + fused softmax partials.
  float v[4][3][4];
#pragma unroll
  for (int ii = 0; ii < 4; ii++) {
    int i = i0 + ii;
    int smv[4];
#pragma unroll
    for (int r = 0; r < 4; r++) {
      int jr = j0 + wave * 16 + kh * 4 + r;
      smv[r] = (jr < L) ? smask[(size_t)i * L + jr] : 0;
    }
#pragma unroll
    for (int tl = 0; tl < 3; tl++) {
      int label = tl * 16 + lj;
      bool lab_ok = label < NLAB;
      float bbv = lab_ok ? b2[label] : 0.f;
#pragma unroll
      for (int r = 0; r < 4; r++) {
        int jr = j0 + wave * 16 + kh * 4 + r;
        float vv = -1e30f;
        if (jr < L && lab_ok) {
          vv = (smv[r] >= 1) ? acc[ii][tl][r] + bbv : 0.f;
          out[(size_t)(b * NLAB + label) * LL + (size_t)i * L + jr] = vv;
        }
        v[ii][tl][r] = vv;
      }
    }
  }
#pragma unroll
  for (int tl = 0; tl < 3; tl++) {
    float mx = -1e30f;
#pragma unroll
    for (int ii = 0; ii < 4; ii++)
#pragma unroll
      for (int r = 0; r < 4; r++) mx = fmaxf(mx, v[ii][tl][r]);
    mx = fmaxf(mx, __shfl_xor(mx, 16, 64));
    mx = fmaxf(mx, __shfl_xor(mx, 32, 64));
    float ssum = 0.f;
#pragma unroll
    for (int ii = 0; ii < 4; ii++)
#pragma unroll
      for (int r = 0; r < 4; r++) {
        float vv = v[ii][tl][r];
        ssum += (vv > -1e29f) ? __expf(vv - mx) : 0.f;
      }
    ssum += __shfl_xor(ssum, 16, 64);
    ssum += __shfl_xor(ssum, 32, 64);
    int label = tl * 16 + lj;
    if (kh == 0 && label < NLAB) {
      int slot = (blockIdx.x * 63 + blockIdx.y) * 4 + wave;
      float2* pp = (float2*)part + (size_t)(b * NLAB + label) * 1024 + slot;
      *pp = make_float2(mx, ssum);
    }
  }
}

// ---------------------------------------------------------------------------
// Finish: grid (8, 72). Each block reduces the 1008 partials of its (b,label)
// (L2-hot, redundant x8) to lse, then subtracts over its slice of out.
// ---------------------------------------------------------------------------
__global__ __launch_bounds__(256) void finish_kernel(const float* __restrict__ part,
                                                     float* __restrict__ out) {
  int bk = blockIdx.y, cx = blockIdx.x;
  int t = threadIdx.x, wave = t >> 6, lane = t & 63;
  const float2* pp = (const float2*)part + (size_t)bk * 1024;
  float m = -1e30f, ss = 0.f;
  for (int idx = t; idx < 1008; idx += 256) {
    float2 q = pp[idx];
    if (q.x > m) { ss = ss * __expf(m - q.x) + q.y; m = q.x; }
    else ss += q.y * __expf(q.x - m);
  }
#pragma unroll
  for (int o = 1; o < 64; o <<= 1) {
    float m2 = __shfl_xor(m, o, 64);
    float s2 = __shfl_xor(ss, o, 64);
    if (m2 > m) { ss = ss * __expf(m - m2) + s2; m = m2; }
    else ss += s2 * __expf(m2 - m);
  }
  __shared__ float rm[4], rs[4], lsh;
  if (lane == 0) { rm[wave] = m; rs[wave] = ss; }
  __syncthreads();
  if (t == 0) {
    float M = rm[0], S = rs[0];
#pragma unroll
    for (int w = 1; w < 4; w++) {
      float m2 = rm[w], s2 = rs[w];
      if (m2 > M) { S = S * __expf(M - m2) + s2; M = m2; }
      else S += s2 * __expf(m2 - M);
    }
    lsh = M + logf(S);
  }
  __syncthreads();
  float l = lsh;
  float4* po = (float4*)(out + (size_t)bk * LL);
  int start = cx * 1985;
  int end = start + 1985; if (end > LL4) end = LL4;
  for (int idx = start + t; idx < end; idx += 256) {
    float4 v = po[idx];
    v.x -= l; v.y -= l; v.z -= l; v.w -= l;
    po[idx] = v;
  }
}

extern "C" void kernel_launch(void* const* d_in, const int* in_sizes, int n_in,
                              void* d_out, int out_size, void* d_ws, size_t ws_size,
                              hipStream_t stream) {
  const float* hidden = (const float*)d_in[0];
  const int* spans    = (const int*)d_in[1];
  const int* smask    = (const int*)d_in[2];
  const float* W1     = (const float*)d_in[3];
  const float* b1     = (const float*)d_in[4];
  const float* W2     = (const float*)d_in[5];
  const float* b2     = (const float*)d_in[6];
  float* ws = (float*)d_ws;
  unsigned short* AJF  = (unsigned short*)(ws + AJF_OFF);
  unsigned short* AiBh = (unsigned short*)(ws + AIB_OFF);
  const uint4* wfr     = (const uint4*)(ws + W2F_OFF);
  float* part          = ws + PART_OFF;
  float* out = (float*)d_out;

  gemm1_kernel<<<dim3(50, 8), 256, 0, stream>>>(b1, W1, W2, hidden, ws, AJF, AiBh);
  main_kernel<<<dim3(4, 63, NB), 256, 0, stream>>>(AJF, AiBh, wfr, b2, spans, smask, out, part);
  finish_kernel<<<dim3(8, NB * NLAB), 256, 0, stream>>>(part, out);
}

// Round 4
// 132.033 us; speedup vs baseline: 1.1524x; 1.1524x over previous
//
#include <hip/hip_runtime.h>
#include <hip/hip_fp16.h>
#include <math.h>

#define L 252
#define HID 768
#define MLP 770
#define NLAB 36
#define NB 2
#define M1 (NB*L)         // 504
#define N1 (2*MLP)        // 1540
#define LL (L*L)          // 63504
#define LL4 (LL/4)        // 15876
#define KC 25             // main K chunks (800 = 25*32)
#define KC1 24            // gemm1 K chunks (768 = 24*32)

typedef float f32x4 __attribute__((ext_vector_type(4)));
typedef _Float16 half8 __attribute__((ext_vector_type(8)));
typedef _Float16 half2v __attribute__((ext_vector_type(2)));

// ---- ws layout (floats) ----
#define AJF_OFF 0                               // fp16 [2][25][16 jt][64][8]
#define AJF_FLOATS 204800
#define AIB_OFF (AJF_OFF + AJF_FLOATS)          // fp16 [3][504][800]
#define AIB_FLOATS 604800
#define W2F_OFF (AIB_OFF + AIB_FLOATS)          // uint4 [25][3][64]
#define W2F_FLOATS 19200
#define PART_OFF (W2F_OFF + W2F_FLOATS)         // float2 [72][1024]
#define PART_FLOATS (72*1024*2)
#define NW2F (KC*3*64)

// B-tile LDS stride (halves): 776 -> row stride 1552B (16B-aligned rows).
#define BSTR 776

__device__ __forceinline__ void dma16(const void* g, void* l) {
  __builtin_amdgcn_global_load_lds(
      (const __attribute__((address_space(1))) unsigned int*)g,
      (__attribute__((address_space(3))) unsigned int*)l, 16, 0, 0);
}

__device__ __forceinline__ unsigned short f16b(float x) {
  _Float16 h = (_Float16)x;
  return *reinterpret_cast<unsigned short*>(&h);
}

// gfx9 s_waitcnt imm: vmcnt[3:0] | expcnt<<4 | lgkmcnt<<8 | vmcnt_hi<<14
#define WAIT_VM5() __builtin_amdgcn_s_waitcnt(0x0F75)   // vmcnt(5)

// ---------------------------------------------------------------------------
// GEMM1 (self-packing, coalesced restructure of r3):
//  - Phase A: block stages its 32 W1 rows (i-half or j-half) into LDS fp16
//    [32][BSTR]. Lane = consecutive k -> every global load is a 256B fully-
//    coalesced wave transaction; the row-half branch is wave-uniform.
//  - K-loop: B-fragments read DIRECTLY from the row-major LDS tile
//    (ds_read_b128 at [nt*16+lj][kc*32+kh*8], 16B-aligned). A-fragments
//    loaded from hidden (fp32, L2-resident) with 2-kc named-register
//    prefetch, cvt fp16 RTE (matches old pack), 4 MFMA / 2-kc iter.
//  - by==0 blocks side-pack W2F -> ws for main (visible at kernel boundary).
// Grid (50, 8), 4 waves, 49664B LDS -> 3 blocks/CU (12 waves/CU).
// ---------------------------------------------------------------------------
__global__ __launch_bounds__(256, 3) void gemm1_kernel(
    const float* __restrict__ b1, const float* __restrict__ W1,
    const float* __restrict__ W2, const float* __restrict__ hidden,
    float* __restrict__ ws, unsigned short* __restrict__ AJF,
    unsigned short* __restrict__ AiBh) {
  __shared__ _Float16 smB[32 * BSTR];   // 49,664 B
  int t = threadIdx.x;
  int wave = t >> 6, lane = t & 63, lj = lane & 15, kh = lane >> 4;
  int nt0 = blockIdx.x * 2;
  int mt = blockIdx.y * 4 + wave;
  int m0 = mt * 16;
  union FU { unsigned u[4]; half8 h8; };

  // --- side job: W2F pack (50 by==0 blocks x 96 entries = 4800) ---
  if (blockIdx.y == 0 && t < 96) {
    int e2 = blockIdx.x * 96 + t;
    int kc = e2 / 192, rem = e2 - kc * 192;
    int tile = rem / 64, ln = rem - tile * 64;
    int label = tile * 16 + (ln & 15);
    int kb = kc * 32 + (ln >> 4) * 8;
    unsigned int u[4];
#pragma unroll
    for (int p = 0; p < 4; p++) {
      unsigned short us[2];
#pragma unroll
      for (int q = 0; q < 2; q++) {
        int k = kb + 2 * p + q;
        float v = (label < NLAB && k < MLP) ? W2[label * MLP + k] : 0.f;
        us[q] = f16b(v);
      }
      u[p] = (unsigned int)us[0] | ((unsigned int)us[1] << 16);
    }
    ((uint4*)(ws + W2F_OFF))[e2] = make_uint4(u[0], u[1], u[2], u[3]);
  }

  // --- Phase A: coalesced stage of 32 B-rows into LDS ---
#pragma unroll
  for (int rr = 0; rr < 8; rr++) {
    int row = wave * 8 + rr;
    int n = nt0 * 16 + row;
    _Float16* dst = smB + (size_t)row * BSTR;
    if (n < MLP) {
      const float* base = W1 + (size_t)n * 1537;
#pragma unroll
      for (int c = 0; c < 12; c++)
        dst[c * 64 + lane] = (_Float16)base[c * 64 + lane];
    } else if (n < N1) {
      const float* base = W1 + (size_t)(n - MLP) * 1537 + HID;
#pragma unroll
      for (int c = 0; c < 12; c++)
        dst[c * 64 + lane] = (_Float16)base[c * 64 + lane];
    } else {
#pragma unroll
      for (int c = 0; c < 12; c++)
        dst[c * 64 + lane] = (_Float16)0.f;
    }
  }
  __syncthreads();

  // --- K-loop: direct-A (2-kc named-reg prefetch) x LDS row-major B ---
  int mrow = m0 + lj;
  const bool mvalid = mrow < M1;
  if (mrow >= M1) mrow = M1 - 1;
  int bb = (mrow >= L) ? 1 : 0;
  const float* aptr = hidden + ((size_t)(bb * (L + 1) + 1 + (mrow - bb * L))) * HID + kh * 8;
  const _Float16* bp0 = smB + (size_t)(0 * 16 + lj) * BSTR + kh * 8;
  const _Float16* bp1 = smB + (size_t)(16 + lj) * BSTR + kh * 8;

  f32x4 acc[2];
  acc[0] = (f32x4)(0.f);
  acc[1] = (f32x4)(0.f);

  float4 c00 = *(const float4*)(aptr);
  float4 c01 = *(const float4*)(aptr + 4);
  float4 c10 = *(const float4*)(aptr + 32);
  float4 c11 = *(const float4*)(aptr + 36);

  for (int kc = 0; kc < KC1; kc += 2) {
    int k2 = (kc + 2 < KC1) ? kc + 2 : kc;
    int k3 = (kc + 3 < KC1) ? kc + 3 : kc;
    float4 n00 = *(const float4*)(aptr + k2 * 32);
    float4 n01 = *(const float4*)(aptr + k2 * 32 + 4);
    float4 n10 = *(const float4*)(aptr + k3 * 32);
    float4 n11 = *(const float4*)(aptr + k3 * 32 + 4);

    // --- kc ---
    {
      uint4 bv0 = *(const uint4*)(bp0 + kc * 32);
      uint4 bv1 = *(const uint4*)(bp1 + kc * 32);
      float cf[8] = {c00.x, c00.y, c00.z, c00.w, c01.x, c01.y, c01.z, c01.w};
      FU af;
#pragma unroll
      for (int p = 0; p < 4; p++) {
        float f0 = mvalid ? cf[2 * p] : 0.f;
        float f1 = mvalid ? cf[2 * p + 1] : 0.f;
        af.u[p] = (unsigned int)f16b(f0) | ((unsigned int)f16b(f1) << 16);
      }
      FU bf0, bf1;
      bf0.u[0] = bv0.x; bf0.u[1] = bv0.y; bf0.u[2] = bv0.z; bf0.u[3] = bv0.w;
      bf1.u[0] = bv1.x; bf1.u[1] = bv1.y; bf1.u[2] = bv1.z; bf1.u[3] = bv1.w;
      acc[0] = __builtin_amdgcn_mfma_f32_16x16x32_f16(af.h8, bf0.h8, acc[0], 0, 0, 0);
      acc[1] = __builtin_amdgcn_mfma_f32_16x16x32_f16(af.h8, bf1.h8, acc[1], 0, 0, 0);
    }
    // --- kc+1 ---
    {
      uint4 bv0 = *(const uint4*)(bp0 + (kc + 1) * 32);
      uint4 bv1 = *(const uint4*)(bp1 + (kc + 1) * 32);
      float cf[8] = {c10.x, c10.y, c10.z, c10.w, c11.x, c11.y, c11.z, c11.w};
      FU af;
#pragma unroll
      for (int p = 0; p < 4; p++) {
        float f0 = mvalid ? cf[2 * p] : 0.f;
        float f1 = mvalid ? cf[2 * p + 1] : 0.f;
        af.u[p] = (unsigned int)f16b(f0) | ((unsigned int)f16b(f1) << 16);
      }
      FU bf0, bf1;
      bf0.u[0] = bv0.x; bf0.u[1] = bv0.y; bf0.u[2] = bv0.z; bf0.u[3] = bv0.w;
      bf1.u[0] = bv1.x; bf1.u[1] = bv1.y; bf1.u[2] = bv1.z; bf1.u[3] = bv1.w;
      acc[0] = __builtin_amdgcn_mfma_f32_16x16x32_f16(af.h8, bf0.h8, acc[0], 0, 0, 0);
      acc[1] = __builtin_amdgcn_mfma_f32_16x16x32_f16(af.h8, bf1.h8, acc[1], 0, 0, 0);
    }
    c00 = n00; c01 = n01; c10 = n10; c11 = n11;
  }

  // --- epilogue: identical semantics to round-2 gemm1 ---
#pragma unroll
  for (int nt = 0; nt < 2; nt++) {
    int nn = (nt0 + nt) * 16 + lj;
    if (nn >= N1) continue;
    if (nn < MLP) {
      float b1v = b1[nn];
      float wv = W1[(size_t)nn * 1537 + 1536];
#pragma unroll
      for (int r = 0; r < 4; r++) {
        int mm = m0 + kh * 4 + r;
        if (mm < M1) {
          float a = acc[nt][r] + b1v;
          AiBh[(size_t)(0 * M1 + mm) * 800 + nn] = f16b(a);
          AiBh[(size_t)(1 * M1 + mm) * 800 + nn] = f16b(a + wv);
          AiBh[(size_t)(2 * M1 + mm) * 800 + nn] = f16b(a + 2.f * wv);
        }
      }
    } else {
      int hh = nn - MLP;
      int kcq = hh >> 5, kk = hh & 31;
      int l2hi = (kk >> 3) << 4, ee = kk & 7;
#pragma unroll
      for (int r = 0; r < 4; r++) {
        int mm = m0 + kh * 4 + r;
        if (mm < M1) {
          int bb2 = (mm >= L) ? 1 : 0;
          int jg = mm - bb2 * L;
          size_t rec = ((size_t)((bb2 * KC + kcq) * 16 + (jg >> 4)) * 64 + (l2hi | (jg & 15)));
          AJF[rec * 8 + ee] = f16b(acc[nt][r]);
        }
      }
    }
  }
}

// ---------------------------------------------------------------------------
// Main: per-wave async pipeline, 2-ahead / 3 buffers, vmcnt(5). fp16 packed
// h-construction: v_pk_add_f16 + v_pk_max_f16 -> mfma_f16 (no repack).
// Block = 64j x 4i x b; wave = j-16-tile. Buf 5KB: aj[0,1K) p[1K,2K) wf[2K,5K).
// ---------------------------------------------------------------------------
__global__ __launch_bounds__(256, 2) void main_kernel(
    const unsigned short* __restrict__ AJF,
    const unsigned short* __restrict__ AiBh,
    const uint4* __restrict__ wfr,
    const float* __restrict__ b2,
    const int* __restrict__ spans,
    const int* __restrict__ smask,
    float* __restrict__ out,
    float* __restrict__ part) {
  __shared__ char sm[61440];
  int t = threadIdx.x;
  int wave = t >> 6, lane = t & 63, lj = lane & 15, kh = lane >> 4;
  int j0 = blockIdx.x * 64;
  int i0 = blockIdx.y * 4;
  int b = blockIdx.z;
  int s = spans[2 * b], e = spans[2 * b + 1];
  int j = j0 + wave * 16 + lj;

  int poff[4];
#pragma unroll
  for (int ii = 0; ii < 4; ii++) {
    int i = i0 + ii;
    int ind = 0;
    if (i == s && j == e) ind = 2;
    else if (s <= i && i <= j && j <= e) ind = 1;
    poff[ii] = 1024 + ((ind * 4 + ii) * 4 + kh) * 16;
  }

  const unsigned short* aj_g = AJF + ((size_t)((b * KC + 0) * 16 + (j0 >> 4) + wave) * 64 + lane) * 8;
  int pr = lane >> 2; if (pr > 11) pr = 11;
  int pt = pr >> 2, pii = pr & 3, pc = lane & 3;
  const unsigned short* p_g = AiBh + (size_t)(pt * M1 + b * L + i0 + pii) * 800 + pc * 8;
  const uint4* wf_g = wfr + lane;
  char* WB = sm + wave * 15360;
  char* bA = WB;
  char* bB = WB + 5120;
  char* bC = WB + 10240;

  f32x4 acc[4][3];
#pragma unroll
  for (int ii = 0; ii < 4; ii++)
#pragma unroll
    for (int tl = 0; tl < 3; tl++) acc[ii][tl] = (f32x4)(0.f);
  union FU { unsigned u[4]; half8 h8; };
  union U2 { unsigned u; half2v h; };

  dma16(aj_g, bA);
  dma16(p_g, bA + 1024);
  dma16(&wf_g[0 * 64], bA + 2048);
  dma16(&wf_g[1 * 64], bA + 3072);
  dma16(&wf_g[2 * 64], bA + 4096);
  dma16(aj_g + 8192, bB);
  dma16(p_g + 32, bB + 1024);
  dma16(&wf_g[3 * 64], bB + 2048);
  dma16(&wf_g[4 * 64], bB + 3072);
  dma16(&wf_g[5 * 64], bB + 4096);

  for (int kc = 0; kc < KC; kc++) {
    WAIT_VM5();
    uint4 av = *(const uint4*)(bA + lane * 16);
    uint4 w0 = *(const uint4*)(bA + 2048 + lane * 16);
    uint4 w1 = *(const uint4*)(bA + 3072 + lane * 16);
    uint4 w2v = *(const uint4*)(bA + 4096 + lane * 16);
    uint4 pv[4];
#pragma unroll
    for (int ii = 0; ii < 4; ii++) pv[ii] = *(const uint4*)(bA + poff[ii]);
    __builtin_amdgcn_sched_barrier(0);
    int kn = kc + 2; if (kn > KC - 1) kn = KC - 1;
    dma16(aj_g + (size_t)kn * 8192, bC);
    dma16(p_g + kn * 32, bC + 1024);
    dma16(&wf_g[(kn * 3 + 0) * 64], bC + 2048);
    dma16(&wf_g[(kn * 3 + 1) * 64], bC + 3072);
    dma16(&wf_g[(kn * 3 + 2) * 64], bC + 4096);
    __builtin_amdgcn_sched_barrier(0);
    { char* tmp = bA; bA = bB; bB = bC; bC = tmp; }
    unsigned avu[4] = {av.x, av.y, av.z, av.w};
    FU wf0, wf1, wf2;
    wf0.u[0] = w0.x; wf0.u[1] = w0.y; wf0.u[2] = w0.z; wf0.u[3] = w0.w;
    wf1.u[0] = w1.x; wf1.u[1] = w1.y; wf1.u[2] = w1.z; wf1.u[3] = w1.w;
    wf2.u[0] = w2v.x; wf2.u[1] = w2v.y; wf2.u[2] = w2v.z; wf2.u[3] = w2v.w;
#pragma unroll
    for (int ii = 0; ii < 4; ii++) {
      unsigned pu[4] = {pv[ii].x, pv[ii].y, pv[ii].z, pv[ii].w};
      FU fr;
#pragma unroll
      for (int q = 0; q < 4; q++) {
        U2 a, p, r;
        a.u = avu[q]; p.u = pu[q];
        half2v sum = a.h + p.h;                       // v_pk_add_f16
        half2v zz = (half2v)((_Float16)0);
        r.h = __builtin_elementwise_max(sum, zz);     // v_pk_max_f16
        fr.u[q] = r.u;
      }
      acc[ii][0] = __builtin_amdgcn_mfma_f32_16x16x32_f16(fr.h8, wf0.h8, acc[ii][0], 0, 0, 0);
      acc[ii][1] = __builtin_amdgcn_mfma_f32_16x16x32_f16(fr.h8, wf1.h8, acc[ii][1], 0, 0, 0);
      acc[ii][2] = __builtin_amdgcn_mfma_f32_16x16x32_f16(fr.h8, wf2.h8, acc[ii][2], 0, 0, 0);
    }
  }

  // Epilogue: masked store + fused softmax partials.
  float v[4][3][4];
#pragma unroll
  for (int ii = 0; ii < 4; ii++) {
    int i = i0 + ii;
    int smv[4];
#pragma unroll
    for (int r = 0; r < 4; r++) {
      int jr = j0 + wave * 16 + kh * 4 + r;
      smv[r] = (jr < L) ? smask[(size_t)i * L + jr] : 0;
    }
#pragma unroll
    for (int tl = 0; tl < 3; tl++) {
      int label = tl * 16 + lj;
      bool lab_ok = label < NLAB;
      float bbv = lab_ok ? b2[label] : 0.f;
#pragma unroll
      for (int r = 0; r < 4; r++) {
        int jr = j0 + wave * 16 + kh * 4 + r;
        float vv = -1e30f;
        if (jr < L && lab_ok) {
          vv = (smv[r] >= 1) ? acc[ii][tl][r] + bbv : 0.f;
          out[(size_t)(b * NLAB + label) * LL + (size_t)i * L + jr] = vv;
        }
        v[ii][tl][r] = vv;
      }
    }
  }
#pragma unroll
  for (int tl = 0; tl < 3; tl++) {
    float mx = -1e30f;
#pragma unroll
    for (int ii = 0; ii < 4; ii++)
#pragma unroll
      for (int r = 0; r < 4; r++) mx = fmaxf(mx, v[ii][tl][r]);
    mx = fmaxf(mx, __shfl_xor(mx, 16, 64));
    mx = fmaxf(mx, __shfl_xor(mx, 32, 64));
    float ssum = 0.f;
#pragma unroll
    for (int ii = 0; ii < 4; ii++)
#pragma unroll
      for (int r = 0; r < 4; r++) {
        float vv = v[ii][tl][r];
        ssum += (vv > -1e29f) ? __expf(vv - mx) : 0.f;
      }
    ssum += __shfl_xor(ssum, 16, 64);
    ssum += __shfl_xor(ssum, 32, 64);
    int label = tl * 16 + lj;
    if (kh == 0 && label < NLAB) {
      int slot = (blockIdx.x * 63 + blockIdx.y) * 4 + wave;
      float2* pp = (float2*)part + (size_t)(b * NLAB + label) * 1024 + slot;
      *pp = make_float2(mx, ssum);
    }
  }
}

// ---------------------------------------------------------------------------
// Finish: grid (8, 72). Each block reduces the 1008 partials of its (b,label)
// (L2-hot, redundant x8) to lse, then subtracts over its slice of out.
// ---------------------------------------------------------------------------
__global__ __launch_bounds__(256) void finish_kernel(const float* __restrict__ part,
                                                     float* __restrict__ out) {
  int bk = blockIdx.y, cx = blockIdx.x;
  int t = threadIdx.x, wave = t >> 6, lane = t & 63;
  const float2* pp = (const float2*)part + (size_t)bk * 1024;
  float m = -1e30f, ss = 0.f;
  for (int idx = t; idx < 1008; idx += 256) {
    float2 q = pp[idx];
    if (q.x > m) { ss = ss * __expf(m - q.x) + q.y; m = q.x; }
    else ss += q.y * __expf(q.x - m);
  }
#pragma unroll
  for (int o = 1; o < 64; o <<= 1) {
    float m2 = __shfl_xor(m, o, 64);
    float s2 = __shfl_xor(ss, o, 64);
    if (m2 > m) { ss = ss * __expf(m - m2) + s2; m = m2; }
    else ss += s2 * __expf(m2 - m);
  }
  __shared__ float rm[4], rs[4], lsh;
  if (lane == 0) { rm[wave] = m; rs[wave] = ss; }
  __syncthreads();
  if (t == 0) {
    float M = rm[0], S = rs[0];
#pragma unroll
    for (int w = 1; w < 4; w++) {
      float m2 = rm[w], s2 = rs[w];
      if (m2 > M) { S = S * __expf(M - m2) + s2; M = m2; }
      else S += s2 * __expf(m2 - M);
    }
    lsh = M + logf(S);
  }
  __syncthreads();
  float l = lsh;
  float4* po = (float4*)(out + (size_t)bk * LL);
  int start = cx * 1985;
  int end = start + 1985; if (end > LL4) end = LL4;
  for (int idx = start + t; idx < end; idx += 256) {
    float4 v = po[idx];
    v.x -= l; v.y -= l; v.z -= l; v.w -= l;
    po[idx] = v;
  }
}

extern "C" void kernel_launch(void* const* d_in, const int* in_sizes, int n_in,
                              void* d_out, int out_size, void* d_ws, size_t ws_size,
                              hipStream_t stream) {
  const float* hidden = (const float*)d_in[0];
  const int* spans    = (const int*)d_in[1];
  const int* smask    = (const int*)d_in[2];
  const float* W1     = (const float*)d_in[3];
  const float* b1     = (const float*)d_in[4];
  const float* W2     = (const float*)d_in[5];
  const float* b2     = (const float*)d_in[6];
  float* ws = (float*)d_ws;
  unsigned short* AJF  = (unsigned short*)(ws + AJF_OFF);
  unsigned short* AiBh = (unsigned short*)(ws + AIB_OFF);
  const uint4* wfr     = (const uint4*)(ws + W2F_OFF);
  float* part          = ws + PART_OFF;
  float* out = (float*)d_out;

  gemm1_kernel<<<dim3(50, 8), 256, 0, stream>>>(b1, W1, W2, hidden, ws, AJF, AiBh);
  main_kernel<<<dim3(4, 63, NB), 256, 0, stream>>>(AJF, AiBh, wfr, b2, spans, smask, out, part);
  finish_kernel<<<dim3(8, NB * NLAB), 256, 0, stream>>>(part, out);
}